// Round 14
// baseline (53.852 us; speedup 1.0000x reference)
//
#include <hip/hip_runtime.h>

// VQ-VAE vector quantizer, MI355X. R11 (best, 34.8us) + K-loop x2 MEASUREMENT round.
//  The second K-loop pass recomputes the GEMM into a dead accumulator (kept alive
//  via asm volatile) through the SAME stage/vmcnt/barrier path, so
//  dur_delta vs R11 == cost of one full K loop. Output path identical to R11.
// z: [16,256,32,32] f32, emb_w: [1024,256] f32
// out: z_q f32 (4194304) ++ loss scalar (1 float)

#define K_CODES 1024
#define D_DIM   256
#define ZQ_SIZE 4194304
#define NBLK    256

typedef unsigned short ushort_t;
typedef unsigned long long u64;
typedef short bf16x8 __attribute__((ext_vector_type(8)));
typedef float f32x16 __attribute__((ext_vector_type(16)));

struct Ctrl { unsigned done; unsigned pad; u64 lsum; };

__device__ __forceinline__ ushort_t f2bf(float x) {
    unsigned int b = __float_as_uint(x);
    b += 0x7fffu + ((b >> 16) & 1u);   // RNE
    return (ushort_t)(b >> 16);
}

__device__ __forceinline__ void gload_lds16(const void* g, void* l) {
    __builtin_amdgcn_global_load_lds(
        (const __attribute__((address_space(1))) void*)g,
        (__attribute__((address_space(3))) void*)l, 16, 0, 0);
}

// ---------------- K1: emb -> Bg (34 planes) ; zero ctrl ----------------
__global__ __launch_bounds__(512) void vq_prep(
        const float* __restrict__ emb, ushort_t* __restrict__ Bg, Ctrl* __restrict__ ctrl) {
    const int gi = blockIdx.x * 512 + threadIdx.x;   // [0, 32768)
    const int k = gi >> 5, g = gi & 31;
    const float4 v0 = *(const float4*)(emb + k * D_DIM + g * 8);
    const float4 v1 = *(const float4*)(emb + k * D_DIM + g * 8 + 4);
    ushort_t o[8];
    o[0] = f2bf(v0.x); o[1] = f2bf(v0.y); o[2] = f2bf(v0.z); o[3] = f2bf(v0.w);
    o[4] = f2bf(v1.x); o[5] = f2bf(v1.y); o[6] = f2bf(v1.z); o[7] = f2bf(v1.w);
    *(bf16x8*)(Bg + ((size_t)g * K_CODES + k) * 8) = *(bf16x8*)o;
    float s = v0.x * v0.x + v0.y * v0.y + v0.z * v0.z + v0.w * v0.w
            + v1.x * v1.x + v1.y * v1.y + v1.z * v1.z + v1.w * v1.w;
#pragma unroll
    for (int off = 16; off >= 1; off >>= 1) s += __shfl_xor(s, off);   // all 32 lanes
    if (g < 2) {   // planes 32,33: replicated bf16(-enorm/32)
        const ushort_t ev = f2bf(s * -0.03125f);
        ushort_t eo[8];
#pragma unroll
        for (int j = 0; j < 8; ++j) eo[j] = ev;
        *(bf16x8*)(Bg + ((size_t)(32 + g) * K_CODES + k) * 8) = *(bf16x8*)eo;
    }
    if (gi == 0) { ctrl->done = 0u; ctrl->lsum = 0ull; }
}

// ---------------- K2: main ----------------
__global__ __launch_bounds__(512, 2) void vq_main(
        const float* __restrict__ z, const float* __restrict__ emb,
        const ushort_t* __restrict__ Bg,
        float* __restrict__ out, float* __restrict__ loss, Ctrl* __restrict__ ctrl) {
    __shared__ __align__(16) char smem[133632];
    ushort_t* As  = (ushort_t*)smem;                 // [32 planes][64 rows][8], 32 KB
    ushort_t* Bs  = (ushort_t*)(smem + 32768);       // 3 x [2][1024][8], 96 KB ring
    float*    et  = (float*)(smem + 32768);          // [64][260] f32 (epilogue, alias Bs)
    float*    znp = (float*)(smem + 131072);         // [64][8] f32 (prologue)
    u64*      pmin = (u64*)(smem + 131072);          // [64][4]     (epilogue, alias znp)
    float*    znL = (float*)(smem + 133120);         // [64]
    int*      idxL = (int*)(smem + 133376);          // [64]

    const int bid = blockIdx.x, tid = threadIdx.x;
    const int b = bid >> 4;
    const int hw0 = (bid & 15) * 64;
    const int w = tid >> 6, l = tid & 63;
    const int wm = w >> 2, wn = w & 3;               // 2 row-groups x 4 code-groups
    const int lane31 = l & 31, hi = l >> 5;

    auto stage = [&](int sbuf, int t) {
#pragma unroll
        for (int qq = 0; qq < 4; ++qq) {
            int g = qq * 512 + tid;                  // [0,2048) granules
            int lp = g >> 10, kk = g & 1023;
            gload_lds16(Bg + ((size_t)(t * 2 + lp) * K_CODES + kk) * 8,
                        Bs + (size_t)sbuf * 16384 + (size_t)g * 8);
        }
    };

    stage(0, 0);
    stage(1, 1);   // chunks 0,1 fly under the prologue; prologue's own waits drain them

    // ---- prologue: z -> As bf16 (direct coalesced loads) + znorm -> znL ----
    {
        const float* zb = z + (size_t)b * (D_DIM * 1024) + hw0;
        const int hw = tid & 63, gs = tid >> 6;      // gs in [0,8)
        float zn = 0.f;
#pragma unroll
        for (int gi = 0; gi < 4; ++gi) {
            const int g = gs * 4 + gi;               // granule plane [0,32)
            float v[8]; ushort_t o[8];
#pragma unroll
            for (int j = 0; j < 8; ++j) v[j] = zb[(size_t)(g * 8 + j) * 1024 + hw];
#pragma unroll
            for (int j = 0; j < 8; ++j) { zn += v[j] * v[j]; o[j] = f2bf(v[j]); }
            *(bf16x8*)(As + ((size_t)g * 64 + hw) * 8) = *(bf16x8*)o;
        }
        znp[hw * 8 + gs] = zn;
        __syncthreads();                             // As + znp ready; drains stage 0,1
        if (tid < 64) {
            float s = 0.f;
#pragma unroll
            for (int g = 0; g < 8; ++g) s += znp[tid * 8 + g];
            znL[tid] = s;
        }
        __syncthreads();                             // znp reads done; znL ready
    }

    // ---- K loop: 17 chunks (last = enorm), 3-buffer counted-vmcnt pipeline ----
    f32x16 acc[8];
#pragma unroll
    for (int cf = 0; cf < 8; ++cf)
#pragma unroll
        for (int r = 0; r < 16; ++r) acc[cf][r] = 0.f;

#define COMPUTE(ACC, BUF, T, ONES) do {                                         \
        const ushort_t* Bp = Bs + (size_t)(BUF) * 16384 +                       \
                             ((size_t)hi * 1024 + wn * 256) * 8;                \
        bf16x8 a;                                                               \
        if (ONES) { _Pragma("unroll")                                           \
            for (int j = 0; j < 8; ++j) a[j] = (short)0x3F80;                   \
        } else {                                                                \
            a = *(const bf16x8*)(As + ((size_t)((T) * 2 + hi) * 64              \
                                       + wm * 32 + lane31) * 8);                \
        }                                                                       \
        __builtin_amdgcn_s_setprio(1);                                          \
        _Pragma("unroll")                                                       \
        for (int cf = 0; cf < 8; ++cf) {                                        \
            const bf16x8 bf = *(const bf16x8*)(Bp + (size_t)(cf * 32 + lane31) * 8); \
            ACC[cf] = __builtin_amdgcn_mfma_f32_32x32x16_bf16(bf, a, ACC[cf], 0, 0, 0); \
        }                                                                       \
        __builtin_amdgcn_s_setprio(0);                                          \
    } while (0)

    int bcur = 0, bnxt = 2;
    for (int t = 0; t < 15; ++t) {
        stage(bnxt, t + 2);                          // buffer (t+2)%3: last read iter t-1
        asm volatile("s_waitcnt vmcnt(8)" ::: "memory");   // chunk t done; t+1,t+2 in flight
        __builtin_amdgcn_s_barrier();
        __builtin_amdgcn_sched_barrier(0);
        COMPUTE(acc, bcur, t, false);
        __builtin_amdgcn_s_barrier();                // all reads of chunk t done
        bcur = (bcur == 2) ? 0 : bcur + 1;
        bnxt = (bnxt == 2) ? 0 : bnxt + 1;
    }
    asm volatile("s_waitcnt vmcnt(4)" ::: "memory");
    __builtin_amdgcn_s_barrier();
    __builtin_amdgcn_sched_barrier(0);
    COMPUTE(acc, bcur, 15, false);
    __builtin_amdgcn_s_barrier();
    bcur = (bcur == 2) ? 0 : bcur + 1;
    asm volatile("s_waitcnt vmcnt(0)" ::: "memory");
    __builtin_amdgcn_s_barrier();
    __builtin_amdgcn_sched_barrier(0);
    COMPUTE(acc, bcur, 16, true);

    // ---- epilogue: lane-local argmax over 128 codes (acc = z.e - enorm/2) ----
    {
        float m = acc[0][0];
#pragma unroll
        for (int cf = 0; cf < 8; ++cf)
#pragma unroll
            for (int r = 0; r < 16; ++r) m = fmaxf(m, acc[cf][r]);
        unsigned cc = 0xffffffffu;
#pragma unroll
        for (int cf = 0; cf < 8; ++cf)
#pragma unroll
            for (int r = 0; r < 16; ++r) {
                const unsigned cst = (unsigned)(cf * 32 + (r & 3) + 8 * (r >> 2));
                if (acc[cf][r] == m) cc = cst < cc ? cst : cc;
            }
        unsigned code = cc + (unsigned)(wn * 256 + 4 * hi);
        const float om = __shfl_xor(m, 32);
        const unsigned oc = __shfl_xor(code, 32);
        if (om > m || (om == m && oc < code)) { m = om; code = oc; }
        unsigned sb = __float_as_uint(m);
        unsigned s = sb ^ (unsigned)(((int)sb >> 31) | 0x80000000);
        u64 key = ((u64)(~s) << 32) | code;          // min key = max score, tie->min code
        __builtin_amdgcn_s_barrier();                // As/acc phase done (pmin aliases znp)
        if (l < 32) pmin[(wm * 32 + lane31) * 4 + wn] = key;
    }
    __syncthreads();

    // ---- final per-row min across 4 code-waves -> idx + loss ----
    if (tid < 64) {
        u64 b0 = pmin[tid * 4], b1 = pmin[tid * 4 + 1];
        u64 b2 = pmin[tid * 4 + 2], b3 = pmin[tid * 4 + 3];
        u64 m01 = b0 < b1 ? b0 : b1;
        u64 m23 = b2 < b3 ? b2 : b3;
        u64 best = m01 < m23 ? m01 : m23;
        idxL[tid] = (int)(best & 1023u);
        unsigned us = ~(unsigned)(best >> 32);
        unsigned fb = (us & 0x80000000u) ? (us ^ 0x80000000u) : ~us;
        float sc = __uint_as_float(fb);              // max(z.e - enorm/2)
        float lp = znL[tid] - 2.0f * sc;             // ||z||^2 + enorm - 2 z.e
#pragma unroll
        for (int off = 32; off >= 1; off >>= 1) lp += __shfl_xor(lp, off);
        if (tid == 0) {
            u64 fix = (u64)(long long)((double)lp * 1048576.0);
            atomicAdd(&ctrl->lsum, fix);
            __threadfence();
            unsigned old = atomicAdd(&ctrl->done, 1u);
            if (old == (NBLK - 1)) {
                __threadfence();
                u64 tot = atomicAdd(&ctrl->lsum, 0ull);
                loss[0] = (float)((double)tot * (1.25 / (1048576.0 * 4194304.0)));
            }
        }
    }

    // ======== MEASUREMENT ONLY: run the K loop a second time (dead result) ======
    // Same staging path + same vmcnt/barrier schedule; result folded to one float
    // and kept alive with asm (rule #17). dur - R11dur == one full K-loop cost.
    asm volatile("s_waitcnt vmcnt(0)" ::: "memory"); // drain atomics/stores (accurate counts)
    __builtin_amdgcn_s_barrier();
    {
        f32x16 accD[8];
#pragma unroll
        for (int cf = 0; cf < 8; ++cf)
#pragma unroll
            for (int r = 0; r < 16; ++r) accD[cf][r] = 0.f;
        stage(0, 0);
        stage(1, 1);
        int dcur = 0, dnxt = 2;
        for (int t = 0; t < 15; ++t) {
            stage(dnxt, t + 2);
            asm volatile("s_waitcnt vmcnt(8)" ::: "memory");
            __builtin_amdgcn_s_barrier();
            __builtin_amdgcn_sched_barrier(0);
            COMPUTE(accD, dcur, t, false);
            __builtin_amdgcn_s_barrier();
            dcur = (dcur == 2) ? 0 : dcur + 1;
            dnxt = (dnxt == 2) ? 0 : dnxt + 1;
        }
        asm volatile("s_waitcnt vmcnt(4)" ::: "memory");
        __builtin_amdgcn_s_barrier();
        __builtin_amdgcn_sched_barrier(0);
        COMPUTE(accD, dcur, 15, false);
        __builtin_amdgcn_s_barrier();
        dcur = (dcur == 2) ? 0 : dcur + 1;
        asm volatile("s_waitcnt vmcnt(0)" ::: "memory");
        __builtin_amdgcn_s_barrier();
        __builtin_amdgcn_sched_barrier(0);
        COMPUTE(accD, dcur, 16, true);
        float md = accD[0][0];
#pragma unroll
        for (int cf = 0; cf < 8; ++cf)
#pragma unroll
            for (int r = 0; r < 16; ++r) md = fmaxf(md, accD[cf][r]);
        asm volatile("" :: "v"(md));                 // keep pass-2 alive, no DCE
    }
#undef COMPUTE
    __syncthreads();   // idxL ready; dummy Bs reads done -> et may overwrite

    // ---- gather emb rows -> et[local row] (1 KB coalesced per wave pass) ----
#pragma unroll
    for (int jj = 0; jj < 8; ++jj) {
        int j = jj * 512 + tid;                      // row = j>>6 in [0,64), gr = j&63
        int mrow = j >> 6, gr = j & 63;
        float4 v = *(const float4*)(emb + (size_t)idxL[mrow] * D_DIM + gr * 4);
        *(float4*)(et + mrow * 260 + gr * 4) = v;
    }
    __syncthreads();

    // ---- out[b][d][hw0+hw] = et[hw][d] ----
    const int hw4 = (tid & 15) * 4;
    const int dr = tid >> 4;                         // 0..31
#pragma unroll
    for (int it = 0; it < 8; ++it) {
        const int d = it * 32 + dr;
        float4 qv;
        qv.x = et[(hw4 + 0) * 260 + d];
        qv.y = et[(hw4 + 1) * 260 + d];
        qv.z = et[(hw4 + 2) * 260 + d];
        qv.w = et[(hw4 + 3) * 260 + d];
        *(float4*)(out + ((size_t)(b * 256 + d)) * 1024 + hw0 + hw4) = qv;
    }
}

extern "C" void kernel_launch(void* const* d_in, const int* in_sizes, int n_in,
                              void* d_out, int out_size, void* d_ws, size_t ws_size,
                              hipStream_t stream) {
    const float* z   = (const float*)d_in[0];
    const float* emb = (const float*)d_in[1];
    float* out  = (float*)d_out;
    float* loss = out + ZQ_SIZE;

    char* ws = (char*)d_ws;
    ushort_t* Bg = (ushort_t*)(ws);           //  557,056 B  [34][1024] 16B granules
    Ctrl* ctrl   = (Ctrl*)(ws + 557056);      //       16 B

    vq_prep<<<64, 512, 0, stream>>>(emb, Bg, ctrl);
    vq_main<<<NBLK, 512, 0, stream>>>(z, emb, Bg, out, loss, ctrl);
}

// Round 15
// 35.597 us; speedup vs baseline: 1.5128x; 1.5128x over previous
//
#include <hip/hip_runtime.h>

// VQ-VAE vector quantizer, MI355X. 2 kernels.
//  K1 vq_prep : emb f32 -> Bg bf16 granule-planar [34][1024][8]; planes 32,33 =
//               bf16(-enorm/32) replicated (enorm baked into GEMM); zero ctrl.
//  K2 vq_main : 256 blocks x 1024 thr (16 waves = 4/SIMD), block = 64 rows x 1024 codes.
//    prologue: z -> As bf16 LDS (read-only after) + znorm -> znL. ONE barrier.
//    K loop:   BARRIER-FREE, waves free-run. B frags global->reg from L2-resident
//              Bg, ping-pong 2-chunk prefetch; each B frag feeds 2 MFMA (a0,a1),
//              each A frag 2 MFMA. 4 MFMA/chunk/wave, acc = 4 named f32x16.
//    epilogue: swapped-operand lane-local argmax -> idx; striped-cell loss;
//              gather emb rows -> et -> out.
// z: [16,256,32,32] f32, emb_w: [1024,256] f32
// out: z_q f32 (4194304) ++ loss scalar (1 float)

#define K_CODES 1024
#define D_DIM   256
#define ZQ_SIZE 4194304
#define NBLK    256

typedef unsigned short ushort_t;
typedef unsigned long long u64;
typedef short bf16x8 __attribute__((ext_vector_type(8)));
typedef float f32x16 __attribute__((ext_vector_type(16)));

struct Ctrl { u64 lsum[32]; unsigned done; unsigned pad[7]; };

__device__ __forceinline__ ushort_t f2bf(float x) {
    unsigned int b = __float_as_uint(x);
    b += 0x7fffu + ((b >> 16) & 1u);   // RNE
    return (ushort_t)(b >> 16);
}

// ---------------- K1: emb -> Bg (34 planes) ; zero ctrl ----------------
__global__ __launch_bounds__(512) void vq_prep(
        const float* __restrict__ emb, ushort_t* __restrict__ Bg, Ctrl* __restrict__ ctrl) {
    const int gi = blockIdx.x * 512 + threadIdx.x;   // [0, 32768)
    const int k = gi >> 5, g = gi & 31;
    const float4 v0 = *(const float4*)(emb + k * D_DIM + g * 8);
    const float4 v1 = *(const float4*)(emb + k * D_DIM + g * 8 + 4);
    ushort_t o[8];
    o[0] = f2bf(v0.x); o[1] = f2bf(v0.y); o[2] = f2bf(v0.z); o[3] = f2bf(v0.w);
    o[4] = f2bf(v1.x); o[5] = f2bf(v1.y); o[6] = f2bf(v1.z); o[7] = f2bf(v1.w);
    *(bf16x8*)(Bg + ((size_t)g * K_CODES + k) * 8) = *(bf16x8*)o;
    float s = v0.x * v0.x + v0.y * v0.y + v0.z * v0.z + v0.w * v0.w
            + v1.x * v1.x + v1.y * v1.y + v1.z * v1.z + v1.w * v1.w;
#pragma unroll
    for (int off = 16; off >= 1; off >>= 1) s += __shfl_xor(s, off);   // all 32 lanes
    if (g < 2) {   // planes 32,33: replicated bf16(-enorm/32)
        const ushort_t ev = f2bf(s * -0.03125f);
        ushort_t eo[8];
#pragma unroll
        for (int j = 0; j < 8; ++j) eo[j] = ev;
        *(bf16x8*)(Bg + ((size_t)(32 + g) * K_CODES + k) * 8) = *(bf16x8*)eo;
    }
    if (gi < 32) ctrl->lsum[gi] = 0ull;
    if (gi == 32) ctrl->done = 0u;
}

// ---------------- K2: main ----------------
// LDS map (bytes):
//   As   [     0, 32768)  [32 planes][64 rows][8] bf16 (K loop; dead after)
//   et   [     0, 66560)  [64][260] f32 (epilogue gather; aliases As)
//   znp  [ 66560, 70656)  [64][16] f32 (prologue partials)
//   pmin [ 66560, 74752)  [64][16] u64 (epilogue; aliases znp)
//   znL  [ 74752, 75008)  [64] f32
//   idxL [ 75008, 75264)  [64] i32
__global__ __launch_bounds__(1024, 4) void vq_main(
        const float* __restrict__ z, const float* __restrict__ emb,
        const ushort_t* __restrict__ Bg,
        float* __restrict__ out, float* __restrict__ loss, Ctrl* __restrict__ ctrl) {
    __shared__ __align__(16) char smem[75264];
    ushort_t* As   = (ushort_t*)smem;
    float*    et   = (float*)smem;
    float*    znp  = (float*)(smem + 66560);
    u64*      pmin = (u64*)(smem + 66560);
    float*    znL  = (float*)(smem + 74752);
    int*      idxL = (int*)(smem + 75008);

    const int bid = blockIdx.x, tid = threadIdx.x;
    const int b = bid >> 4;
    const int hw0 = (bid & 15) * 64;
    const int w = tid >> 6, l = tid & 63;            // wave w owns codes [w*64, w*64+64)
    const int lane31 = l & 31, hi = l >> 5;

    // B frag load (global->reg, L2-resident): plane = t*2+hi, codes w*64 + cf*32 + lane31
    auto loadB = [&](int t, bf16x8* bb) {
        const ushort_t* p = Bg + (((size_t)(t * 2 + hi)) * K_CODES + w * 64 + lane31) * 8;
        bb[0] = *(const bf16x8*)(p);
        bb[1] = *(const bf16x8*)(p + 32 * 8);
    };

    bf16x8 bA[2], bB[2];
    loadB(0, bA);                                    // chunks 0,1 fly under the prologue
    loadB(1, bB);

    // ---- prologue: z -> As bf16 (coalesced 256B-segment loads) + znorm ----
    {
        const float* zb = z + (size_t)b * (D_DIM * 1024) + hw0;
        const int hw = l, gs = w;                    // gs in [0,16)
        float zn = 0.f;
#pragma unroll
        for (int gi = 0; gi < 2; ++gi) {
            const int g = gs * 2 + gi;               // granule plane [0,32)
            float v[8]; ushort_t o[8];
#pragma unroll
            for (int j = 0; j < 8; ++j) v[j] = zb[(size_t)(g * 8 + j) * 1024 + hw];
#pragma unroll
            for (int j = 0; j < 8; ++j) { zn += v[j] * v[j]; o[j] = f2bf(v[j]); }
            *(bf16x8*)(As + ((size_t)g * 64 + hw) * 8) = *(bf16x8*)o;
        }
        znp[hw * 16 + gs] = zn;
        __syncthreads();                             // As + znp ready
        if (tid < 64) {
            float s = 0.f;
#pragma unroll
            for (int g = 0; g < 16; ++g) s += znp[tid * 16 + g];
            znL[tid] = s;                            // wave-0 local; read later by wave 0
        }
    }

    // ---- K loop: 17 chunks, barrier-free, reg ping-pong 2-ahead ----
    f32x16 acc00, acc01, acc10, acc11;               // [cf][row-half]
#pragma unroll
    for (int r = 0; r < 16; ++r) { acc00[r] = 0.f; acc01[r] = 0.f; acc10[r] = 0.f; acc11[r] = 0.f; }

#define COMPUTE(T, BB) do {                                                       \
        const bf16x8 a0 = *(const bf16x8*)(As + ((size_t)((T) * 2 + hi) * 64 + lane31) * 8);      \
        const bf16x8 a1 = *(const bf16x8*)(As + ((size_t)((T) * 2 + hi) * 64 + 32 + lane31) * 8); \
        __builtin_amdgcn_s_setprio(1);                                            \
        acc00 = __builtin_amdgcn_mfma_f32_32x32x16_bf16(BB[0], a0, acc00, 0, 0, 0); \
        acc01 = __builtin_amdgcn_mfma_f32_32x32x16_bf16(BB[0], a1, acc01, 0, 0, 0); \
        acc10 = __builtin_amdgcn_mfma_f32_32x32x16_bf16(BB[1], a0, acc10, 0, 0, 0); \
        acc11 = __builtin_amdgcn_mfma_f32_32x32x16_bf16(BB[1], a1, acc11, 0, 0, 0); \
        __builtin_amdgcn_s_setprio(0);                                            \
    } while (0)

#pragma unroll
    for (int tt = 0; tt < 8; ++tt) {                 // chunks 2tt, 2tt+1
        COMPUTE(2 * tt, bA);
        loadB(2 * tt + 2, bA);                       // 2tt+2 <= 16
        COMPUTE(2 * tt + 1, bB);
        if (tt < 7) loadB(2 * tt + 3, bB);
    }
    {   // chunk 16 = enorm planes (32,33): A-side = all-ones (16k x -enorm/32 = -enorm/2)
        bf16x8 aone;
#pragma unroll
        for (int j = 0; j < 8; ++j) aone[j] = (short)0x3F80;   // bf16 1.0
        __builtin_amdgcn_s_setprio(1);
        acc00 = __builtin_amdgcn_mfma_f32_32x32x16_bf16(bA[0], aone, acc00, 0, 0, 0);
        acc01 = __builtin_amdgcn_mfma_f32_32x32x16_bf16(bA[0], aone, acc01, 0, 0, 0);
        acc10 = __builtin_amdgcn_mfma_f32_32x32x16_bf16(bA[1], aone, acc10, 0, 0, 0);
        acc11 = __builtin_amdgcn_mfma_f32_32x32x16_bf16(bA[1], aone, acc11, 0, 0, 0);
        __builtin_amdgcn_s_setprio(0);
    }
#undef COMPUTE

    // ---- epilogue: lane-local argmax (acc = z.e - enorm/2), row mi*32+lane31 ----
#define REDUCE_ROW(A0, A1, MI) do {                                              \
        float m = A0[0];                                                         \
        _Pragma("unroll")                                                        \
        for (int r = 0; r < 16; ++r) m = fmaxf(m, A0[r]);                        \
        _Pragma("unroll")                                                        \
        for (int r = 0; r < 16; ++r) m = fmaxf(m, A1[r]);                        \
        unsigned cc = 0xffffffffu;                                               \
        _Pragma("unroll")                                                        \
        for (int r = 0; r < 16; ++r) {                                           \
            const unsigned c0 = (unsigned)((r & 3) + 8 * (r >> 2));              \
            if (A0[r] == m) cc = c0 < cc ? c0 : cc;                              \
            const unsigned c1 = c0 + 32u;                                        \
            if (A1[r] == m && c1 < cc) cc = c1;                                  \
        }                                                                        \
        unsigned code = cc + (unsigned)(w * 64 + 4 * hi);                        \
        const float om = __shfl_xor(m, 32);                                      \
        const unsigned oc = __shfl_xor(code, 32);                                \
        if (om > m || (om == m && oc < code)) { m = om; code = oc; }             \
        unsigned sb = __float_as_uint(m);                                        \
        unsigned s = sb ^ (unsigned)(((int)sb >> 31) | 0x80000000);              \
        u64 key = ((u64)(~s) << 32) | code;                                      \
        if (l < 32) pmin[((MI) * 32 + lane31) * 16 + w] = key;                   \
    } while (0)

    REDUCE_ROW(acc00, acc10, 0);                     // row lane31: cf0 codes 0-31, cf1 32-63
    REDUCE_ROW(acc01, acc11, 1);                     // row 32+lane31
#undef REDUCE_ROW
    __syncthreads();

    // ---- final per-row min across 16 waves -> idx + striped loss ----
    if (tid < 64) {
        u64 best = pmin[tid * 16];
#pragma unroll
        for (int i = 1; i < 16; ++i) { u64 qv = pmin[tid * 16 + i]; if (qv < best) best = qv; }
        idxL[tid] = (int)(best & 1023u);
        unsigned us = ~(unsigned)(best >> 32);
        unsigned fb = (us & 0x80000000u) ? (us ^ 0x80000000u) : ~us;
        float sc = __uint_as_float(fb);              // max(z.e - enorm/2)
        float lp = znL[tid] - 2.0f * sc;             // ||z||^2 + enorm - 2 z.e
#pragma unroll
        for (int off = 32; off >= 1; off >>= 1) lp += __shfl_xor(lp, off);
        if (tid == 0) {
            u64 fix = (u64)(long long)((double)lp * 1048576.0);
            atomicAdd(&ctrl->lsum[bid & 31], fix);   // <=8 blocks per cell
            __threadfence();
            unsigned old = atomicAdd(&ctrl->done, 1u);
            if (old == (NBLK - 1)) {
                __threadfence();
                u64 tot = 0ull;
#pragma unroll
                for (int i = 0; i < 32; ++i) tot += atomicAdd(&ctrl->lsum[i], 0ull);
                loss[0] = (float)((double)tot * (1.25 / (1048576.0 * 4194304.0)));
            }
        }
    }
    __syncthreads();   // idxL ready; As dead -> et may overwrite

    // ---- gather emb rows -> et[local row] (1 KB coalesced per wave pass) ----
#pragma unroll
    for (int jj = 0; jj < 4; ++jj) {
        int j = jj * 1024 + tid;                     // row = j>>6 in [0,64), gr = j&63
        int mrow = j >> 6, gr = j & 63;
        float4 v = *(const float4*)(emb + (size_t)idxL[mrow] * D_DIM + gr * 4);
        *(float4*)(et + mrow * 260 + gr * 4) = v;
    }
    __syncthreads();

    // ---- out[b][d][hw0+hw] = et[hw][d] ----
    const int hw4 = (tid & 15) * 4;
    const int dr = tid >> 4;                         // 0..63
#pragma unroll
    for (int it = 0; it < 4; ++it) {
        const int d = it * 64 + dr;
        float4 qv;
        qv.x = et[(hw4 + 0) * 260 + d];
        qv.y = et[(hw4 + 1) * 260 + d];
        qv.z = et[(hw4 + 2) * 260 + d];
        qv.w = et[(hw4 + 3) * 260 + d];
        *(float4*)(out + ((size_t)(b * 256 + d)) * 1024 + hw0 + hw4) = qv;
    }
}

extern "C" void kernel_launch(void* const* d_in, const int* in_sizes, int n_in,
                              void* d_out, int out_size, void* d_ws, size_t ws_size,
                              hipStream_t stream) {
    const float* z   = (const float*)d_in[0];
    const float* emb = (const float*)d_in[1];
    float* out  = (float*)d_out;
    float* loss = out + ZQ_SIZE;

    char* ws = (char*)d_ws;
    ushort_t* Bg = (ushort_t*)(ws);           //  557,056 B  [34][1024] 16B granules
    Ctrl* ctrl   = (Ctrl*)(ws + 557056);      //      288 B

    vq_prep<<<64, 512, 0, stream>>>(emb, Bg, ctrl);
    vq_main<<<NBLK, 1024, 0, stream>>>(z, emb, Bg, out, loss, ctrl);
}